// Round 4
// baseline (1657.799 us; speedup 1.0000x reference)
//
#include <hip/hip_runtime.h>
#include <stdint.h>
#include <math.h>

// EncoderSRNN: T=127 steps, BSZ=32 items, HDIM=256, SDIM=128, SSZ=128.
// One WG (512 threads = 8 waves, 2 waves/SIMD -> 256 VGPR budget) per item.
// All GEMV weights register-resident as f16 (192 VGPR/thread), v_dot2_f32_f16.
// Stack f32 in LDS, column-parallel conflict-free update. buf recurrence
// collapsed to a 128-coeff scalar window over precomputed E2H (emb@We2h^T).

#define T_STEPS 127

// flat f32 output offsets (outputs, hid, stack, acts, top_elems)
#define OUT_OFF   0
#define HID_OFF   1040384
#define STACK_OFF 1048576
#define ACTS_OFF  1572864
#define TE_OFF    1580992

// ws layout (uint4 granularity for weight blobs):
//  uint4 [0,16384):      W1 = s2h/h2h, per-srnn-thread 32 uint4: w1r[i]=ws4[i*512+tid]
//  uint4 [16384,24576):  W23 = h2s/s2u, per-thread 16 uint4: w23r[i]=ws4[16384+i*512+tid]
//  uint4 [24576,32768):  W0 = We2h^T packed [k-chunk][j] for prep_e2h
//  uint  [131072,393216): E2H f16-pairs per item: [b][r2*256+j] = (row2r2,row2r2+1)
#define E2H_OFF_U 131072

typedef _Float16 h2 __attribute__((ext_vector_type(2)));

__device__ __forceinline__ unsigned packh2(float a, float b){
  h2 v; v.x = (_Float16)a; v.y = (_Float16)b;
  return __builtin_bit_cast(unsigned, v);
}
__device__ __forceinline__ float h2loF(unsigned u){ h2 v = __builtin_bit_cast(h2,u); return (float)v.x; }
__device__ __forceinline__ float h2hiF(unsigned u){ h2 v = __builtin_bit_cast(h2,u); return (float)v.y; }

#if __has_builtin(__builtin_amdgcn_fdot2)
__device__ __forceinline__ float fdot2(unsigned a, unsigned b, float c){
  return __builtin_amdgcn_fdot2(__builtin_bit_cast(h2,a), __builtin_bit_cast(h2,b), c, false);
}
#else
__device__ __forceinline__ float fdot2(unsigned a, unsigned b, float c){
  return c + h2loF(a)*h2loF(b) + h2hiF(a)*h2hiF(b);
}
#endif

// ---------------- prep: pack all weights to f16 blobs ----------------
__global__ void prep_pack(const float* __restrict__ We2h, const float* __restrict__ Ws2h,
                          const float* __restrict__ Wh2h, const float* __restrict__ Wh2s,
                          const float* __restrict__ Ws2u, uint4* __restrict__ out4){
  int gid = blockIdx.x*256 + threadIdx.x;    // [0, 32768)
  const float* src;
  if (gid < 16384){                          // W1: i in [0,32), t in [0,512)
    int i = gid >> 9, t_ = gid & 511;
    int aside = t_ >> 8, ar = t_ & 255;
    const float* S = aside ? Wh2h : Ws2h;
    int ajp = ar >> 1, aks = ar & 1;
    int j  = 2*ajp + (i >> 4);
    int k0 = aks*128 + (i & 15)*8;
    src = S + j*256 + k0;
  } else if (gid < 24576){                   // W23: i in [0,16), t in [0,512)
    int l = gid - 16384;
    int i = l >> 9, t_ = l & 511;
    int hside = t_ >> 8, r = t_ & 255;
    const float* S = hside ? Ws2u : Wh2s;
    int jr = r >> 2, ksb = r & 3;
    int j  = 2*jr + (i >> 3);
    int k0 = ksb*64 + (i & 7)*8;
    src = S + j*256 + k0;
  } else {                                   // W0: [k-chunk i8][j]
    int l = gid - 24576;
    int i8 = l >> 8, j = l & 255;
    src = We2h + j*256 + i8*8;
  }
  uint4 r4;
  r4.x = packh2(src[0], src[1]); r4.y = packh2(src[2], src[3]);
  r4.z = packh2(src[4], src[5]); r4.w = packh2(src[6], src[7]);
  out4[gid] = r4;
}

// ---------------- prep: E2H = emb @ We2h^T, f16 row-pairs ----------------
__global__ void prep_e2h(const int* __restrict__ inputs, const float* __restrict__ embW,
                         const uint4* __restrict__ w04, unsigned* __restrict__ e2hpk){
  __shared__ float emb[8][256];
  int tid = threadIdx.x;
  int r2 = blockIdx.x >> 3, bg = blockIdx.x & 7;
  for (int q=0;q<8;q++){
    int rr = q >> 2, bb = q & 3;
    int tok = inputs[(2*r2+rr)*32 + bg*4+bb];
    emb[q][tid] = embW[tok*256 + tid];
  }
  __syncthreads();
  float acc[8] = {0.f,0.f,0.f,0.f,0.f,0.f,0.f,0.f};
  for (int i8=0;i8<32;i8++){
    uint4 u = w04[i8*256 + tid];
    unsigned uu[4] = {u.x,u.y,u.z,u.w};
    #pragma unroll
    for (int c=0;c<4;c++){
      float lo = h2loF(uu[c]), hi = h2hiF(uu[c]);
      int k = i8*8 + c*2;
      #pragma unroll
      for (int q=0;q<8;q++)
        acc[q] += emb[q][k]*lo + emb[q][k+1]*hi;
    }
  }
  int base = (bg*4)*8192 + r2*256 + tid;
  #pragma unroll
  for (int bb=0;bb<4;bb++)
    e2hpk[base + bb*8192] = packh2(acc[bb], acc[4+bb]);  // (row 2r2, row 2r2+1)
}

// ---------------- main sequential kernel ----------------
__global__ __attribute__((amdgpu_flat_work_group_size(512,512), amdgpu_waves_per_eu(2,2)))
void srnn_main(const uint4* __restrict__ ws4, const unsigned* __restrict__ wsu,
               const float* __restrict__ b_e2h, const float* __restrict__ b_s2h,
               const float* __restrict__ b_h2h, const float* __restrict__ Wh2i,
               const float* __restrict__ b_h2i, const float* __restrict__ b_h2s,
               const float* __restrict__ b_s2u, const float* __restrict__ empty_el,
               float* __restrict__ out)
{
  __shared__ __align__(16) float    stk_s[128*128];     // stack f32, 64 KB
  __shared__ __align__(16) unsigned e2h_s[32*258];      // f16 pairs, stride 258
  __shared__ __align__(16) unsigned s_pk[128];          // tops (rows 0,1) f16 pairs
  __shared__ __align__(16) unsigned hid_pk[128];        // hid f16 pairs
  __shared__ __align__(16) float    pv_s[128], uv_s[128];
  __shared__ __align__(16) float    accih[256], acchp[256];
  __shared__ __align__(16) float    emptyf_s[128];
  __shared__ float    wbuf[2][192];
  __shared__ unsigned pkwc[32];
  __shared__ float    partsum[12];
  __shared__ float    pp_s, pq_s;

  const int tid = threadIdx.x;
  const int b   = blockIdx.x;
  // phase A: aside 0 = ihid (s2h + window), 1 = hid-pre (h2h)
  const int aside = tid >> 8;
  const int ar  = tid & 255;
  const int ajp = ar >> 1;              // output pair 0..127
  const int aks = ar & 1;               // K-split 2 (K=128 each)
  // phase B: hside 0 = h2s(new hid), 1 = s2u(old tops)
  const int hside = tid >> 8;
  const int r   = tid & 255;
  const int jr  = r >> 2;               // output pair 0..63
  const int ksb = r & 3;                // K-split 4 (K=64 each)
  // stack: wave g handles 16 rows, lane cp = column pair
  const int g   = tid >> 6;             // 0..7
  const int cp  = tid & 63;

  // ---- preload weights into registers (192 VGPRs) ----
  uint4 w1r[32], w23r[16];
  #pragma unroll
  for (int i=0;i<32;i++) w1r[i]  = ws4[i*512 + tid];
  #pragma unroll
  for (int i=0;i<16;i++) w23r[i] = ws4[16384 + i*512 + tid];

  float bA0=0.f, bA1=0.f;
  if (aks==0){
    int j0 = 2*ajp;
    if (aside==0){ bA0 = b_e2h[j0]+b_s2h[j0]; bA1 = b_e2h[j0+1]+b_s2h[j0+1]; }
    else         { bA0 = b_h2h[j0];           bA1 = b_h2h[j0+1]; }
  }
  float bB0=0.f, bB1=0.f;
  if (ksb==0){
    const float* bb = hside ? b_s2u : b_h2s;
    bB0 = bb[2*jr]; bB1 = bb[2*jr+1];
  }
  float rW0=0.f,rW1=0.f,rW2=0.f;
  if (tid<256){ rW0=Wh2i[tid]; rW1=Wh2i[256+tid]; rW2=Wh2i[512+tid]; }
  const float bi0=b_h2i[0], bi1=b_h2i[1], bi2=b_h2i[2];

  // ---- init LDS state ----
  const unsigned* e2hg = wsu + E2H_OFF_U + b*8192;
  #pragma unroll
  for (int q=0;q<16;q++){
    int idx = q*512 + tid;
    e2h_s[(idx>>8)*258 + (idx&255)] = e2hg[idx];
  }
  {
    float2 e2 = *(const float2*)&empty_el[2*cp];
    #pragma unroll
    for (int j=0;j<16;j++)
      *(float2*)&stk_s[(16*g+j)*128 + 2*cp] = e2;
  }
  if (tid < 128){
    emptyf_s[tid] = empty_el[tid];
    hid_pk[tid] = 0u;
    int cu = tid & 63;
    s_pk[tid] = packh2(empty_el[2*cu], empty_el[2*cu+1]);
  }
  if (tid < 192){ wbuf[0][tid] = (tid==64)?1.f:0.f; wbuf[1][tid]=0.f; }
  if (tid < 32)  pkwc[tid] = (tid==0)? packh2(1.f,0.f) : 0u;
  __syncthreads();

  int cur = 0;
  for (int t=0;t<T_STEPS;++t){
    // ============ Phase A: ihid (s2h + inp-window) & hid-pre (h2h) ============
    {
      const uint4* act4 = ((const uint4*)(aside ? hid_pk : s_pk)) + aks*16;
      float x0 = 0.f, x1 = 0.f;
      if (aside==0){
        #pragma unroll 4
        for (int q=0;q<16;q++){
          int r2 = aks*16 + q;
          unsigned cw = pkwc[r2];
          uint2 e = *(const uint2*)&e2h_s[r2*258 + 2*ajp];
          x0 = fdot2(cw, e.x, x0);
          x1 = fdot2(cw, e.y, x1);
        }
      }
      #pragma unroll 4
      for (int i=0;i<16;i++){
        uint4 A  = act4[i];
        uint4 Wa = w1r[i], Wb = w1r[16+i];
        x0 = fdot2(A.x,Wa.x,x0); x0 = fdot2(A.y,Wa.y,x0);
        x0 = fdot2(A.z,Wa.z,x0); x0 = fdot2(A.w,Wa.w,x0);
        x1 = fdot2(A.x,Wb.x,x1); x1 = fdot2(A.y,Wb.y,x1);
        x1 = fdot2(A.z,Wb.z,x1); x1 = fdot2(A.w,Wb.w,x1);
      }
      x0 += __shfl_xor(x0,1);
      x1 += __shfl_xor(x1,1);
      if (aks==0){
        float* dst = aside ? acchp : accih;
        *(float2*)&dst[2*ajp] = make_float2(x0 + bA0, x1 + bA1);
      }
    }
    __syncthreads();                                   // B1

    // ---- hid update + inst partials ----
    if (tid < 128){
      float2 ih2 = *(const float2*)&accih[2*tid];
      float2 hp2 = *(const float2*)&acchp[2*tid];
      float hn0 = fmaxf(ih2.x+hp2.x, 0.f);
      float hn1 = fmaxf(ih2.y+hp2.y, 0.f);
      hid_pk[tid] = packh2(hn0,hn1);
      *(float2*)&out[OUT_OFF + t*8192 + b*256 + 2*tid] = make_float2(hn0,hn1);
      if (t==T_STEPS-1) *(float2*)&out[HID_OFF + b*256 + 2*tid] = make_float2(hn0,hn1);
    }
    if (tid < 256){
      float v = accih[tid];
      float p0=v*rW0, p1=v*rW1, p2=v*rW2;
      #pragma unroll
      for (int o=32;o>=1;o>>=1){ p0+=__shfl_xor(p0,o); p1+=__shfl_xor(p1,o); p2+=__shfl_xor(p2,o); }
      if ((tid&63)==0){ int w=tid>>6; partsum[w*3]=p0; partsum[w*3+1]=p1; partsum[w*3+2]=p2; }
    }
    __syncthreads();                                   // B2

    // ---- softmax/gating on wave 0 (overlaps phase B of the other waves) ----
    if (tid < 64){
      float i0 = bi0+partsum[0]+partsum[3]+partsum[6]+partsum[9];
      float i1 = bi1+partsum[1]+partsum[4]+partsum[7]+partsum[10];
      float gi = bi2+partsum[2]+partsum[5]+partsum[8]+partsum[11];
      float mx = fmaxf(i0,i1);
      float e0 = expf(i0-mx), e1 = expf(i1-mx);
      float inv = 1.f/(e0+e1);
      float act0 = e0*inv, act1 = e1*inv;
      float gamma = 1.f + log1pf(expf(gi));
      float A0 = powf(act0,gamma), A1 = powf(act1,gamma);
      float sden = A0+A1+1e-16f;
      float ppv = A0/sden, pqv = A1/sden;
      if (tid==0){
        pp_s = ppv; pq_s = pqv;
        *(float2*)&out[ACTS_OFF + t*64 + b*2] = make_float2(ppv,pqv);
      }
    }

    // ============ Phase B: h2s (new hid) & s2u (old tops) ============
    {
      const uint4* act4b = ((const uint4*)(hside ? s_pk : hid_pk)) + ksb*8;
      float y0 = 0.f, y1 = 0.f;
      #pragma unroll 4
      for (int i=0;i<8;i++){
        uint4 A  = act4b[i];
        uint4 Wa = w23r[i], Wb = w23r[8+i];
        y0 = fdot2(A.x,Wa.x,y0); y0 = fdot2(A.y,Wa.y,y0);
        y0 = fdot2(A.z,Wa.z,y0); y0 = fdot2(A.w,Wa.w,y0);
        y1 = fdot2(A.x,Wb.x,y1); y1 = fdot2(A.y,Wb.y,y1);
        y1 = fdot2(A.z,Wb.z,y1); y1 = fdot2(A.w,Wb.w,y1);
      }
      y0 += __shfl_xor(y0,1); y0 += __shfl_xor(y0,2);
      y1 += __shfl_xor(y1,1); y1 += __shfl_xor(y1,2);
      if (ksb==0){
        float* dst = hside ? uv_s : pv_s;
        *(float2*)&dst[2*jr] = make_float2(fmaxf(y0+bB0,0.f), fmaxf(y1+bB1,0.f));
      }
    }
    __syncthreads();                                   // B3
    const float pp = pp_s, pq = pq_s;

    // ============ Stack update: column-parallel, in-place combine ============
    {
      float2 w[18];                                    // rows 16g-1 .. 16g+16
      #pragma unroll
      for (int k=0;k<18;k++){
        int rr = 16*g - 1 + k;
        if (rr >= 0 && rr <= 127)
          w[k] = *(const float2*)&stk_s[rr*128 + 2*cp];
      }
      if (g == 7) w[17] = *(const float2*)&emptyf_s[2*cp];
      float2 pv2 = make_float2(0.f,0.f), uv2 = make_float2(0.f,0.f);
      if (g == 0){ pv2 = *(const float2*)&pv_s[2*cp]; uv2 = *(const float2*)&uv_s[2*cp]; }
      // coefficient recurrence for the collapsed buf + next-step packed pairs
      if (tid < 128){
        int k = 64+tid;
        wbuf[cur^1][k] = pp*wbuf[cur][k] + pq*wbuf[cur][k-1];
      } else if (tid < 160){
        int r2 = tid-128;
        int k1 = 65 + t - 2*r2;
        float wa = wbuf[cur][k1], wb2 = wbuf[cur][k1-1], wc2 = wbuf[cur][k1-2];
        pkwc[r2] = packh2(pp*wa+pq*wb2, pp*wb2+pq*wc2);
      }
      __syncthreads();                                 // S_e (all stk reads done)
      #pragma unroll
      for (int j=0;j<16;j++){                          // in-place: w[j] <- new row 16g+j
        w[j].x = pp*w[j].x + pq*w[j+2].x;
        w[j].y = pp*w[j].y + pq*w[j+2].y;
      }
      if (g == 0){
        w[0].x = pp*pv2.x + pq*uv2.x;
        w[0].y = pp*pv2.y + pq*uv2.y;
      }
      #pragma unroll
      for (int j=0;j<16;j++)
        *(float2*)&stk_s[(16*g+j)*128 + 2*cp] = w[j];
      if (g == 0){
        *(float2*)&out[TE_OFF + t*4096 + b*128 + 2*cp] = w[0];
        s_pk[cp]    = packh2(w[0].x, w[0].y);
        s_pk[64+cp] = packh2(w[1].x, w[1].y);
      }
    }
    __syncthreads();                                   // S_f
    cur ^= 1;
  }

  // ---- final stack output ----
  #pragma unroll
  for (int j=0;j<16;j++){
    int rr = 16*g + j;
    *(float2*)&out[STACK_OFF + b*16384 + rr*128 + 2*cp] =
      *(const float2*)&stk_s[rr*128 + 2*cp];
  }
}

extern "C" void kernel_launch(void* const* d_in, const int* in_sizes, int n_in,
                              void* d_out, int out_size, void* d_ws, size_t ws_size,
                              hipStream_t stream){
  const int*   inputs = (const int*)d_in[0];
  const float* embW   = (const float*)d_in[1];
  const float* We2h   = (const float*)d_in[2];
  const float* b_e2h  = (const float*)d_in[3];
  const float* Ws2h   = (const float*)d_in[4];
  const float* b_s2h  = (const float*)d_in[5];
  const float* Wh2h   = (const float*)d_in[6];
  const float* b_h2h  = (const float*)d_in[7];
  const float* Wh2i   = (const float*)d_in[8];
  const float* b_h2i  = (const float*)d_in[9];
  const float* Wh2s   = (const float*)d_in[10];
  const float* b_h2s  = (const float*)d_in[11];
  const float* Ws2u   = (const float*)d_in[12];
  const float* b_s2u  = (const float*)d_in[13];
  const float* empty  = (const float*)d_in[14];
  unsigned* wsu = (unsigned*)d_ws;

  prep_pack<<<dim3(128), dim3(256), 0, stream>>>(We2h, Ws2h, Wh2h, Wh2s, Ws2u, (uint4*)wsu);
  prep_e2h<<<dim3(256), dim3(256), 0, stream>>>(inputs, embW, ((const uint4*)wsu)+24576, wsu + E2H_OFF_U);
  srnn_main<<<dim3(32), dim3(512), 0, stream>>>((const uint4*)wsu, (const unsigned*)wsu,
                                                b_e2h, b_s2h, b_h2h, Wh2i, b_h2i,
                                                b_h2s, b_s2u, empty, (float*)d_out);
}

// Round 5
// 1041.723 us; speedup vs baseline: 1.5914x; 1.5914x over previous
//
#include <hip/hip_runtime.h>
#include <stdint.h>
#include <math.h>

// EncoderSRNN: T=127 steps, BSZ=32 items, HDIM=256, SDIM=128, SSZ=128.
// One WG (512 threads = 8 waves = 2 waves/SIMD -> 256-VGPR budget) per item.
// GEMV weights register-resident as f16 (192 VGPR/thread) -- ALL loops touching
// weight arrays are FULLY unrolled so SROA can promote them (R2-R4 spilled to
// scratch because partial unroll left dynamic indices). v_dot2_f32_f16, f32 acc.
// Stack f32 in LDS, column-parallel update. buf recurrence collapsed to a
// 128-coeff scalar window over precomputed E2H (emb@We2h^T), emb_W[PAD]==0.

#define T_STEPS 127

// flat f32 output offsets (outputs, hid, stack, acts, top_elems)
#define OUT_OFF   0
#define HID_OFF   1040384
#define STACK_OFF 1048576
#define ACTS_OFF  1572864
#define TE_OFF    1580992

// ws layout (uint4 granularity):
//  uint4 [0,16384):      W1: phase-A weights. thread t_=(aside*256+j), w1r[i]=ws4[i*512+t_]
//                        = (aside? Wh2h : Ws2h)[j][8i..8i+7]
//  uint4 [16384,24576):  W23: phase-B. t_=(hside*256 + jb*2 + ks), w23r[i]=ws4[16384+i*512+t_]
//                        = (hside? Ws2u : Wh2s)[jb][ks*128 + 8i .. +7]
//  uint4 [24576,32768):  W0 = We2h^T packed [k-chunk i8][j] for prep_e2h
//  uint  [131072,393216): E2H f16-pairs per item: [b][r2*256+j] = (row 2r2, row 2r2+1)
#define E2H_OFF_U 131072

typedef _Float16 h2 __attribute__((ext_vector_type(2)));

__device__ __forceinline__ unsigned packh2(float a, float b){
  h2 v; v.x = (_Float16)a; v.y = (_Float16)b;
  return __builtin_bit_cast(unsigned, v);
}
__device__ __forceinline__ float h2loF(unsigned u){ h2 v = __builtin_bit_cast(h2,u); return (float)v.x; }
__device__ __forceinline__ float h2hiF(unsigned u){ h2 v = __builtin_bit_cast(h2,u); return (float)v.y; }

#if __has_builtin(__builtin_amdgcn_fdot2)
__device__ __forceinline__ float fdot2(unsigned a, unsigned b, float c){
  return __builtin_amdgcn_fdot2(__builtin_bit_cast(h2,a), __builtin_bit_cast(h2,b), c, false);
}
#else
__device__ __forceinline__ float fdot2(unsigned a, unsigned b, float c){
  return c + h2loF(a)*h2loF(b) + h2hiF(a)*h2hiF(b);
}
#endif

// ---------------- prep: pack all weights to f16 blobs ----------------
__global__ void prep_pack(const float* __restrict__ We2h, const float* __restrict__ Ws2h,
                          const float* __restrict__ Wh2h, const float* __restrict__ Wh2s,
                          const float* __restrict__ Ws2u, uint4* __restrict__ out4){
  int gid = blockIdx.x*256 + threadIdx.x;    // [0, 32768)
  const float* src;
  if (gid < 16384){                          // W1: i in [0,32), t_ in [0,512)
    int i = gid >> 9, t_ = gid & 511;
    int aside = t_ >> 8, j = t_ & 255;
    const float* S = aside ? Wh2h : Ws2h;
    src = S + j*256 + i*8;
  } else if (gid < 24576){                   // W23: i in [0,16), t_ in [0,512)
    int l = gid - 16384;
    int i = l >> 9, t_ = l & 511;
    int hside = t_ >> 8, r = t_ & 255;
    int jb = r >> 1, ks = r & 1;
    const float* S = hside ? Ws2u : Wh2s;
    src = S + jb*256 + ks*128 + i*8;
  } else {                                   // W0: [k-chunk i8][j]
    int l = gid - 24576;
    int i8 = l >> 8, j = l & 255;
    src = We2h + j*256 + i8*8;
  }
  uint4 r4;
  r4.x = packh2(src[0], src[1]); r4.y = packh2(src[2], src[3]);
  r4.z = packh2(src[4], src[5]); r4.w = packh2(src[6], src[7]);
  out4[gid] = r4;
}

// ---------------- prep: E2H = emb @ We2h^T, f16 row-pairs ----------------
__global__ void prep_e2h(const int* __restrict__ inputs, const float* __restrict__ embW,
                         const uint4* __restrict__ w04, unsigned* __restrict__ e2hpk){
  __shared__ float emb[8][256];
  int tid = threadIdx.x;
  int r2 = blockIdx.x >> 3, bg = blockIdx.x & 7;
  for (int q=0;q<8;q++){
    int rr = q >> 2, bb = q & 3;
    int tok = inputs[(2*r2+rr)*32 + bg*4+bb];
    emb[q][tid] = embW[tok*256 + tid];
  }
  __syncthreads();
  float acc[8] = {0.f,0.f,0.f,0.f,0.f,0.f,0.f,0.f};
  for (int i8=0;i8<32;i8++){
    uint4 u = w04[i8*256 + tid];
    unsigned uu[4] = {u.x,u.y,u.z,u.w};
    #pragma unroll
    for (int c=0;c<4;c++){
      float lo = h2loF(uu[c]), hi = h2hiF(uu[c]);
      int k = i8*8 + c*2;
      #pragma unroll
      for (int q=0;q<8;q++)
        acc[q] += emb[q][k]*lo + emb[q][k+1]*hi;
    }
  }
  int base = (bg*4)*8192 + r2*256 + tid;
  #pragma unroll
  for (int bb=0;bb<4;bb++)
    e2hpk[base + bb*8192] = packh2(acc[bb], acc[4+bb]);  // (row 2r2, row 2r2+1)
}

// ---------------- main sequential kernel ----------------
__global__ __attribute__((amdgpu_flat_work_group_size(512,512), amdgpu_waves_per_eu(2,2)))
void srnn_main(const uint4* __restrict__ ws4, const unsigned* __restrict__ wsu,
               const float* __restrict__ b_e2h, const float* __restrict__ b_s2h,
               const float* __restrict__ b_h2h, const float* __restrict__ Wh2i,
               const float* __restrict__ b_h2i, const float* __restrict__ b_h2s,
               const float* __restrict__ b_s2u, const float* __restrict__ empty_el,
               float* __restrict__ out)
{
  __shared__ __align__(16) float    stk_s[128*128];     // stack f32, 64 KB
  __shared__ __align__(16) unsigned e2h_s[32*258];      // f16 pairs, stride 258
  __shared__ __align__(16) unsigned s_pk[128];          // tops (rows 0,1) f16 pairs
  __shared__ __align__(16) unsigned hid_pk[128];        // hid f16 pairs
  __shared__ __align__(16) float    pv_s[128], uv_s[128];
  __shared__ __align__(16) float    accih[256], acchp[256];
  __shared__ __align__(16) float    emptyf_s[128];
  __shared__ float    wbuf[2][192];
  __shared__ unsigned pkwc[32];
  __shared__ float    partsum[12];
  __shared__ float    pp_s, pq_s;

  const int tid = threadIdx.x;
  const int b   = blockIdx.x;
  // phase A: 1 output per thread, full K=256
  const int aside = tid >> 8;           // 0: ihid (s2h + window), 1: hid-pre (h2h)
  const int aj  = tid & 255;            // output index 0..255
  // phase B: 1 output per thread, K-split 2
  const int hside = tid >> 8;           // 0: pv (h2s, new hid), 1: uv (s2u, old tops)
  const int jb  = (tid & 255) >> 1;     // output 0..127
  const int ks  = tid & 1;              // K half
  // stack: wave g handles 16 rows, lane cp = column pair
  const int g   = tid >> 6;             // 0..7
  const int cp  = tid & 63;

  // ---- preload weights into registers (192 VGPRs) -- FULL unroll, const idx ----
  uint4 w1r[32], w23r[16];
  #pragma unroll
  for (int i=0;i<32;i++) w1r[i]  = ws4[i*512 + tid];
  #pragma unroll
  for (int i=0;i<16;i++) w23r[i] = ws4[16384 + i*512 + tid];

  float bA = aside ? b_h2h[aj] : (b_e2h[aj] + b_s2h[aj]);
  float bB = (hside ? b_s2u : b_h2s)[jb];
  float rW0=0.f,rW1=0.f,rW2=0.f;
  if (tid<256){ rW0=Wh2i[tid]; rW1=Wh2i[256+tid]; rW2=Wh2i[512+tid]; }
  const float bi0=b_h2i[0], bi1=b_h2i[1], bi2=b_h2i[2];

  // ---- init LDS state ----
  const unsigned* e2hg = wsu + E2H_OFF_U + b*8192;
  #pragma unroll
  for (int q=0;q<16;q++){
    int idx = q*512 + tid;
    e2h_s[(idx>>8)*258 + (idx&255)] = e2hg[idx];
  }
  {
    float2 e2 = *(const float2*)&empty_el[2*cp];
    for (int j=0;j<16;j++)
      *(float2*)&stk_s[(16*g+j)*128 + 2*cp] = e2;
  }
  if (tid < 128){
    emptyf_s[tid] = empty_el[tid];
    hid_pk[tid] = 0u;
    int cu = tid & 63;
    s_pk[tid] = packh2(empty_el[2*cu], empty_el[2*cu+1]);
  }
  if (tid < 192){ wbuf[0][tid] = (tid==64)?1.f:0.f; wbuf[1][tid]=0.f; }
  if (tid < 32)  pkwc[tid] = (tid==0)? packh2(1.f,0.f) : 0u;
  __syncthreads();

  int cur = 0;
  for (int t=0;t<T_STEPS;++t){
    // ============ Phase A: ihid (s2h + inp-window) & hid-pre (h2h) ============
    {
      const uint4* act4 = (const uint4*)(aside ? hid_pk : s_pk);  // broadcast reads
      float accA[4] = {0.f,0.f,0.f,0.f};
      #pragma unroll
      for (int i=0;i<32;i++){
        uint4 A = act4[i];
        uint4 W = w1r[i];
        float s = accA[i&3];
        s = fdot2(A.x,W.x,s); s = fdot2(A.y,W.y,s);
        s = fdot2(A.z,W.z,s); s = fdot2(A.w,W.w,s);
        accA[i&3] = s;
      }
      float acc = (accA[0]+accA[1]) + (accA[2]+accA[3]);
      if (aside==0){
        float accW0=0.f, accW1=0.f;
        #pragma unroll
        for (int r2=0;r2<32;r2+=2){
          accW0 = fdot2(pkwc[r2],   e2h_s[r2*258     + aj], accW0);
          accW1 = fdot2(pkwc[r2+1], e2h_s[(r2+1)*258 + aj], accW1);
        }
        accih[aj] = acc + accW0 + accW1 + bA;
      } else {
        acchp[aj] = acc + bA;
      }
    }
    __syncthreads();                                   // B1

    // ---- hid update + inst partials ----
    if (tid < 128){
      float2 ih2 = *(const float2*)&accih[2*tid];
      float2 hp2 = *(const float2*)&acchp[2*tid];
      float hn0 = fmaxf(ih2.x+hp2.x, 0.f);
      float hn1 = fmaxf(ih2.y+hp2.y, 0.f);
      hid_pk[tid] = packh2(hn0,hn1);
      *(float2*)&out[OUT_OFF + t*8192 + b*256 + 2*tid] = make_float2(hn0,hn1);
      if (t==T_STEPS-1) *(float2*)&out[HID_OFF + b*256 + 2*tid] = make_float2(hn0,hn1);
    }
    if (tid < 256){
      float v = accih[tid];
      float p0=v*rW0, p1=v*rW1, p2=v*rW2;
      #pragma unroll
      for (int o=32;o>=1;o>>=1){ p0+=__shfl_xor(p0,o); p1+=__shfl_xor(p1,o); p2+=__shfl_xor(p2,o); }
      if ((tid&63)==0){ int w=tid>>6; partsum[w*3]=p0; partsum[w*3+1]=p1; partsum[w*3+2]=p2; }
    }
    __syncthreads();                                   // B2

    // ---- softmax/gating on wave 0 (overlaps phase B of the other waves) ----
    if (tid < 64){
      float i0 = bi0+partsum[0]+partsum[3]+partsum[6]+partsum[9];
      float i1 = bi1+partsum[1]+partsum[4]+partsum[7]+partsum[10];
      float gi = bi2+partsum[2]+partsum[5]+partsum[8]+partsum[11];
      float mx = fmaxf(i0,i1);
      float e0 = expf(i0-mx), e1 = expf(i1-mx);
      float inv = 1.f/(e0+e1);
      float act0 = e0*inv, act1 = e1*inv;
      float gamma = 1.f + log1pf(expf(gi));
      float A0 = powf(act0,gamma), A1 = powf(act1,gamma);
      float sden = A0+A1+1e-16f;
      float ppv = A0/sden, pqv = A1/sden;
      if (tid==0){
        pp_s = ppv; pq_s = pqv;
        *(float2*)&out[ACTS_OFF + t*64 + b*2] = make_float2(ppv,pqv);
      }
    }

    // ============ Phase B: h2s (new hid) & s2u (old tops) ============
    {
      const uint4* act4b = ((const uint4*)(hside ? s_pk : hid_pk)) + ks*16;
      float accB0=0.f, accB1=0.f;
      #pragma unroll
      for (int i=0;i<16;i+=2){
        uint4 A0_ = act4b[i],   W0_ = w23r[i];
        uint4 A1_ = act4b[i+1], W1_ = w23r[i+1];
        accB0 = fdot2(A0_.x,W0_.x,accB0); accB0 = fdot2(A0_.y,W0_.y,accB0);
        accB0 = fdot2(A0_.z,W0_.z,accB0); accB0 = fdot2(A0_.w,W0_.w,accB0);
        accB1 = fdot2(A1_.x,W1_.x,accB1); accB1 = fdot2(A1_.y,W1_.y,accB1);
        accB1 = fdot2(A1_.z,W1_.z,accB1); accB1 = fdot2(A1_.w,W1_.w,accB1);
      }
      float y = accB0 + accB1;
      y += __shfl_xor(y,1);
      if (ks==0){
        float* dst = hside ? uv_s : pv_s;
        dst[jb] = fmaxf(y + bB, 0.f);
      }
    }
    __syncthreads();                                   // B3
    const float pp = pp_s, pq = pq_s;

    // ============ Stack update: column-parallel, in-place combine ============
    {
      float2 w[18];                                    // rows 16g-1 .. 16g+16
      #pragma unroll
      for (int k=0;k<18;k++){
        int rr = 16*g - 1 + k;
        if (rr >= 0 && rr <= 127)
          w[k] = *(const float2*)&stk_s[rr*128 + 2*cp];
      }
      if (g == 7) w[17] = *(const float2*)&emptyf_s[2*cp];
      float2 pv2 = make_float2(0.f,0.f), uv2 = make_float2(0.f,0.f);
      if (g == 0){ pv2 = *(const float2*)&pv_s[2*cp]; uv2 = *(const float2*)&uv_s[2*cp]; }
      // coefficient recurrence for the collapsed buf + next-step packed pairs
      if (tid < 128){
        int k = 64+tid;
        wbuf[cur^1][k] = pp*wbuf[cur][k] + pq*wbuf[cur][k-1];
      } else if (tid < 160){
        int r2 = tid-128;
        int k1 = 65 + t - 2*r2;
        float wa = wbuf[cur][k1], wb2 = wbuf[cur][k1-1], wc2 = wbuf[cur][k1-2];
        pkwc[r2] = packh2(pp*wa+pq*wb2, pp*wb2+pq*wc2);
      }
      __syncthreads();                                 // S_e (all stk reads done)
      #pragma unroll
      for (int j=0;j<16;j++){                          // in-place: w[j] <- new row 16g+j
        w[j].x = pp*w[j].x + pq*w[j+2].x;
        w[j].y = pp*w[j].y + pq*w[j+2].y;
      }
      if (g == 0){
        w[0].x = pp*pv2.x + pq*uv2.x;
        w[0].y = pp*pv2.y + pq*uv2.y;
      }
      #pragma unroll
      for (int j=0;j<16;j++)
        *(float2*)&stk_s[(16*g+j)*128 + 2*cp] = w[j];
      if (g == 0){
        *(float2*)&out[TE_OFF + t*4096 + b*128 + 2*cp] = w[0];
        s_pk[cp]    = packh2(w[0].x, w[0].y);
        s_pk[64+cp] = packh2(w[1].x, w[1].y);
      }
    }
    __syncthreads();                                   // S_f
    cur ^= 1;
  }

  // ---- final stack output ----
  for (int j=0;j<16;j++){
    int rr = 16*g + j;
    *(float2*)&out[STACK_OFF + b*16384 + rr*128 + 2*cp] =
      *(const float2*)&stk_s[rr*128 + 2*cp];
  }
}

extern "C" void kernel_launch(void* const* d_in, const int* in_sizes, int n_in,
                              void* d_out, int out_size, void* d_ws, size_t ws_size,
                              hipStream_t stream){
  const int*   inputs = (const int*)d_in[0];
  const float* embW   = (const float*)d_in[1];
  const float* We2h   = (const float*)d_in[2];
  const float* b_e2h  = (const float*)d_in[3];
  const float* Ws2h   = (const float*)d_in[4];
  const float* b_s2h  = (const float*)d_in[5];
  const float* Wh2h   = (const float*)d_in[6];
  const float* b_h2h  = (const float*)d_in[7];
  const float* Wh2i   = (const float*)d_in[8];
  const float* b_h2i  = (const float*)d_in[9];
  const float* Wh2s   = (const float*)d_in[10];
  const float* b_h2s  = (const float*)d_in[11];
  const float* Ws2u   = (const float*)d_in[12];
  const float* b_s2u  = (const float*)d_in[13];
  const float* empty  = (const float*)d_in[14];
  unsigned* wsu = (unsigned*)d_ws;

  prep_pack<<<dim3(128), dim3(256), 0, stream>>>(We2h, Ws2h, Wh2h, Wh2s, Ws2u, (uint4*)wsu);
  prep_e2h<<<dim3(256), dim3(256), 0, stream>>>(inputs, embW, ((const uint4*)wsu)+24576, wsu + E2H_OFF_U);
  srnn_main<<<dim3(32), dim3(512), 0, stream>>>((const uint4*)wsu, (const unsigned*)wsu,
                                                b_e2h, b_s2h, b_h2h, Wh2i, b_h2i,
                                                b_h2s, b_s2u, empty, (float*)d_out);
}